// Round 4
// baseline (468.781 us; speedup 1.0000x reference)
//
#include <hip/hip_runtime.h>
#include <hip/hip_bf16.h>
#include <math.h>

typedef __bf16 bhalf8 __attribute__((ext_vector_type(8)));
typedef __bf16 bhalf4 __attribute__((ext_vector_type(4)));
typedef float  f32x4  __attribute__((ext_vector_type(4)));

#define MFMA16(a, b, c) __builtin_amdgcn_mfma_f32_16x16x32_bf16(a, b, c, 0, 0, 0)

// ---------------------------------------------------------------------------
// cast f32 -> bf16
// ---------------------------------------------------------------------------
__global__ __launch_bounds__(256) void cast_bf16(const float* __restrict__ in,
                                                 __bf16* __restrict__ out, int n4)
{
  const int i = blockIdx.x * 256 + threadIdx.x;
  if (i < n4) {
    float4 v = ((const float4*)in)[i];
    bhalf4 o;
    o[0] = (__bf16)v.x; o[1] = (__bf16)v.y; o[2] = (__bf16)v.z; o[3] = (__bf16)v.w;
    ((bhalf4*)out)[i] = o;
  }
}

// ---------------------------------------------------------------------------
// transpose+cast: W [K][N] f32 -> Wt [N][K] bf16
// ---------------------------------------------------------------------------
__global__ __launch_bounds__(256) void transcast(const float* __restrict__ W,
                                                 __bf16* __restrict__ Wt, int K, int N)
{
  const int k = blockIdx.x * 64 + (threadIdx.x & 63);
  const int n = blockIdx.y * 4 + (threadIdx.x >> 6);
  Wt[(size_t)n * K + k] = (__bf16)W[(size_t)k * N + n];
}

// ---------------------------------------------------------------------------
// bf16 MFMA GEMM: C[M][N] = A[M][K] @ Bt[N][K]^T
// OUT_MODE 0: bf16 C; 1: f32 C; 2: attention-Q epilogue -> qup/qvp
//   mode2: m = i*4+b, n = head*64+d; writes bf16((acc + pb{u,v}[n]) * 0.125)
//   to q{u,v}p[(b*8+head)*512 + i][d] (pre-biased, pre-scaled Q operands).
// ---------------------------------------------------------------------------
template <int OUT_MODE>
__global__ __launch_bounds__(256) void gemm_bf16(
    const __bf16* __restrict__ A, const __bf16* __restrict__ Bt,
    void* __restrict__ C, int M, int N, int K,
    const float* __restrict__ pbu, const float* __restrict__ pbv,
    __bf16* __restrict__ qup, __bf16* __restrict__ qvp)
{
  __shared__ __bf16 a_lds[128][40];
  __shared__ __bf16 b_lds[128][40];
  const int m0 = blockIdx.x * 128;
  const int n0 = blockIdx.y * 128;
  const int tid = threadIdx.x;
  const int w = tid >> 6, l = tid & 63;
  const int wn = (w >> 1) * 64, wm = (w & 1) * 64;
  const int li = l & 15, lq = l >> 4;
  const int lk = lq << 3;

  f32x4 acc[4][4] = {};

  for (int k0 = 0; k0 < K; k0 += 32) {
    __syncthreads();
#pragma unroll
    for (int c = 0; c < 2; ++c) {
      const int chunk = c * 256 + tid;
      const int row = chunk >> 2, kc = (chunk & 3) << 3;
      *(bhalf8*)&a_lds[row][kc] = *(const bhalf8*)(A + (size_t)(m0 + row) * K + k0 + kc);
      *(bhalf8*)&b_lds[row][kc] = *(const bhalf8*)(Bt + (size_t)(n0 + row) * K + k0 + kc);
    }
    __syncthreads();
    bhalf8 af[4], bf_[4];
#pragma unroll
    for (int s = 0; s < 4; ++s) {
      af[s]  = *(const bhalf8*)&b_lds[wn + s * 16 + li][lk];
      bf_[s] = *(const bhalf8*)&a_lds[wm + s * 16 + li][lk];
    }
#pragma unroll
    for (int ns = 0; ns < 4; ++ns)
#pragma unroll
      for (int ms = 0; ms < 4; ++ms)
        acc[ns][ms] = MFMA16(af[ns], bf_[ms], acc[ns][ms]);
  }

  const int lr = lq << 2;
#pragma unroll
  for (int ms = 0; ms < 4; ++ms) {
    const int m = m0 + wm + ms * 16 + li;
#pragma unroll
    for (int ns = 0; ns < 4; ++ns) {
      const int n = n0 + wn + ns * 16 + lr;
      if (OUT_MODE == 1) {
        *(f32x4*)((float*)C + (size_t)m * N + n) = acc[ns][ms];
      } else if (OUT_MODE == 0) {
        bhalf4 pk;
#pragma unroll
        for (int r = 0; r < 4; ++r) pk[r] = (__bf16)acc[ns][ms][r];
        *(bhalf4*)((__bf16*)C + (size_t)m * N + n) = pk;
      } else {
        const int i = m >> 2, bb = m & 3, hd = n >> 6;
        float4 u4 = *(const float4*)(pbu + n);
        float4 v4 = *(const float4*)(pbv + n);
        const size_t off = (((size_t)bb * 8 + hd) * 512 + i) * 64 + (n & 63);
        bhalf4 pu, pv;
        pu[0] = (__bf16)((acc[ns][ms][0] + u4.x) * 0.125f);
        pu[1] = (__bf16)((acc[ns][ms][1] + u4.y) * 0.125f);
        pu[2] = (__bf16)((acc[ns][ms][2] + u4.z) * 0.125f);
        pu[3] = (__bf16)((acc[ns][ms][3] + u4.w) * 0.125f);
        pv[0] = (__bf16)((acc[ns][ms][0] + v4.x) * 0.125f);
        pv[1] = (__bf16)((acc[ns][ms][1] + v4.y) * 0.125f);
        pv[2] = (__bf16)((acc[ns][ms][2] + v4.z) * 0.125f);
        pv[3] = (__bf16)((acc[ns][ms][3] + v4.w) * 0.125f);
        *(bhalf4*)(qup + off) = pu;
        *(bhalf4*)(qvp + off) = pv;
      }
    }
  }
}

// ---------------------------------------------------------------------------
// V transpose: vtb[plane][d][t]
// ---------------------------------------------------------------------------
__global__ __launch_bounds__(256) void vtrans(const __bf16* __restrict__ kvb,
                                              __bf16* __restrict__ vtb)
{
  __shared__ __bf16 T2[64][72];
  const int t0 = blockIdx.x * 64;
  const int p = blockIdx.y;
  const int b = p >> 3, n = p & 7;
  const int tid = threadIdx.x;
#pragma unroll
  for (int c = 0; c < 2; ++c) {
    const int e = c * 256 + tid;
    const int tl = e >> 3, d8 = (e & 7) << 3;
    bhalf8 v8 = *(const bhalf8*)(kvb + ((size_t)(t0 + tl) * 4 + b) * 1024 + 512 + n * 64 + d8);
#pragma unroll
    for (int j = 0; j < 8; ++j) T2[d8 + j][tl] = v8[j];
  }
  __syncthreads();
#pragma unroll
  for (int c = 0; c < 2; ++c) {
    const int e = c * 256 + tid;
    const int d = e >> 3, t8 = (e & 7) << 3;
    bhalf8 v = *(const bhalf8*)&T2[d][t8];
    *(bhalf8*)(vtb + ((size_t)p * 64 + d) * 2048 + t0 + t8) = v;
  }
}

// ---------------------------------------------------------------------------
// Fused flash attention (as round 3, but Q from pre-biased/scaled qup/qvp).
// ---------------------------------------------------------------------------
__global__ __launch_bounds__(512, 4) void attn_v3(
    const __bf16* __restrict__ qup, const __bf16* __restrict__ qvp,
    const __bf16* __restrict__ kvb, const __bf16* __restrict__ relb,
    const __bf16* __restrict__ vtb, const float* __restrict__ indice,
    __bf16* __restrict__ vecb, float* __restrict__ ml)
{
  __shared__ __align__(16) __bf16 P_l[32][136];
  __shared__ __align__(16) __bf16 bdl[160][33];
  __shared__ float red0[8][33];
  __shared__ float red1[8][33];
  __shared__ float lfin[32];

  const int bid = blockIdx.x;
  const int wrk = ((bid & 7) << 6) + (bid >> 3);
  const int plane = wrk >> 4;
  const int i0 = (wrk & 15) << 5;
  const int b = plane >> 3, n = plane & 7;
  const int tid = threadIdx.x;
  const int w = tid >> 6;
  const int l = tid & 63;
  const int li = l & 15;
  const int lq = l >> 4;

  const __bf16* kbase = kvb + (size_t)b * 1024 + n * 64;
  const __bf16* rbase = relb + (size_t)b * 512 + n * 64;
  const __bf16* vbase = vtb + (size_t)plane * 131072;

  bhalf8 qu[2][2], qv[2][2];
  float g[2][4];
#pragma unroll
  for (int it = 0; it < 2; ++it) {
    const int i = i0 + it * 16 + li;
    const float* gp = indice + ((size_t)i * 4 + b) * 4;
    g[it][0] = gp[0]; g[it][1] = gp[1]; g[it][2] = gp[2]; g[it][3] = gp[3];
    const __bf16* qp = qup + ((size_t)plane * 512 + i) * 64;
    const __bf16* qq = qvp + ((size_t)plane * 512 + i) * 64;
    qu[it][0] = *(const bhalf8*)(qp + lq * 8);
    qu[it][1] = *(const bhalf8*)(qp + 32 + lq * 8);
    qv[it][0] = *(const bhalf8*)(qq + lq * 8);
    qv[it][1] = *(const bhalf8*)(qq + 32 + lq * 8);
  }

  float m0 = -1e30f, m1 = -1e30f, l0 = 0.f, l1 = 0.f;
  f32x4 oacc = {0.f, 0.f, 0.f, 0.f};
  const int dgw = w >> 1, itw = w & 1;
  const int nt = ((1536 + i0 + 31) >> 7) + 1;

  for (int tile = 0; tile < nt; ++tile) {
    const int tb = tile << 7;
    const int rb = tb + 480 - i0;

    // ---- BD ----
#pragma unroll
    for (int ri = 0; ri < 2; ++ri) {
      const int rs = w + ri * 8;
      if (ri == 0 || rs < 10) {
        int row = rb + rs * 16 + li;
        row = row > 2047 ? 2047 : row;
        const __bf16* rp = rbase + (size_t)row * 2048;
        bhalf8 a0 = *(const bhalf8*)(rp + lq * 8);
        bhalf8 a1 = *(const bhalf8*)(rp + 32 + lq * 8);
#pragma unroll
        for (int it = 0; it < 2; ++it) {
          f32x4 c = {0.f, 0.f, 0.f, 0.f};
          c = MFMA16(a0, qv[it][0], c);
          c = MFMA16(a1, qv[it][1], c);
#pragma unroll
          for (int r = 0; r < 4; ++r) {
            const int rowl = rs * 16 + lq * 4 + r;
            int rk = (rb + rowl) >> 9; rk = rk > 3 ? 3 : rk;
            bdl[rowl][it * 16 + li] = (__bf16)(c[r] * g[it][rk]);
          }
        }
      }
    }
    // ---- AC ----
    f32x4 s[2];
    {
      const __bf16* kp = kbase + (size_t)(tb + w * 16 + li) * 4096;
      bhalf8 a0 = *(const bhalf8*)(kp + lq * 8);
      bhalf8 a1 = *(const bhalf8*)(kp + 32 + lq * 8);
#pragma unroll
      for (int it = 0; it < 2; ++it) {
        f32x4 c = {0.f, 0.f, 0.f, 0.f};
        c = MFMA16(a0, qu[it][0], c);
        c = MFMA16(a1, qu[it][1], c);
        s[it] = c;
      }
    }
    __syncthreads();   // bd visible

    float sv[2][4];
    float tmax[2] = {-1e30f, -1e30f};
#pragma unroll
    for (int it = 0; it < 2; ++it) {
      const int i = i0 + it * 16 + li;
#pragma unroll
      for (int r = 0; r < 4; ++r) {
        const int tl = w * 16 + lq * 4 + r;
        const int t = tb + tl;
        float sc = -1e30f;
        if (t <= 1536 + i) {
          const float bdv = (float)bdl[tl + 31 - it * 16 - li][it * 16 + li];
          sc = s[it][r] * g[it][t >> 9] + bdv;
        }
        sv[it][r] = sc;
        tmax[it] = fmaxf(tmax[it], sc);
      }
    }
    tmax[0] = fmaxf(tmax[0], __shfl_xor(tmax[0], 16));
    tmax[0] = fmaxf(tmax[0], __shfl_xor(tmax[0], 32));
    tmax[1] = fmaxf(tmax[1], __shfl_xor(tmax[1], 16));
    tmax[1] = fmaxf(tmax[1], __shfl_xor(tmax[1], 32));
    if (l < 16) { red0[w][li] = tmax[0]; red0[w][16 + li] = tmax[1]; }
    __syncthreads();

    float mn[2], scl[2];
#pragma unroll
    for (int it = 0; it < 2; ++it) {
      const int ic = it * 16 + li;
      float mt = red0[0][ic];
#pragma unroll
      for (int ww = 1; ww < 8; ++ww) mt = fmaxf(mt, red0[ww][ic]);
      const float mo = it ? m1 : m0;
      mn[it] = fmaxf(mo, mt);
      scl[it] = __expf(mo - mn[it]);
    }
    float ps[2] = {0.f, 0.f};
#pragma unroll
    for (int it = 0; it < 2; ++it) {
      bhalf4 pk;
#pragma unroll
      for (int r = 0; r < 4; ++r) {
        const float p = __expf(sv[it][r] - mn[it]);
        ps[it] += p;
        pk[r] = (__bf16)p;
      }
      *(bhalf4*)&P_l[it * 16 + li][w * 16 + lq * 4] = pk;
    }
    ps[0] += __shfl_xor(ps[0], 16); ps[0] += __shfl_xor(ps[0], 32);
    ps[1] += __shfl_xor(ps[1], 16); ps[1] += __shfl_xor(ps[1], 32);
    if (l < 16) { red1[w][li] = ps[0]; red1[w][16 + li] = ps[1]; }
    __syncthreads();

    {
      float ls0 = 0.f, ls1 = 0.f;
#pragma unroll
      for (int ww = 0; ww < 8; ++ww) { ls0 += red1[ww][li]; ls1 += red1[ww][16 + li]; }
      l0 = l0 * scl[0] + ls0; m0 = mn[0];
      l1 = l1 * scl[1] + ls1; m1 = mn[1];
    }
    // ---- PV ----
    oacc *= scl[itw];
    {
      const __bf16* vp = vbase + (size_t)(dgw * 16 + li) * 2048 + tb;
#pragma unroll
      for (int kt = 0; kt < 4; ++kt) {
        bhalf8 af = *(const bhalf8*)(vp + kt * 32 + lq * 8);
        bhalf8 bf_ = *(const bhalf8*)&P_l[itw * 16 + li][kt * 32 + lq * 8];
        oacc = MFMA16(af, bf_, oacc);
      }
    }
  }

  __syncthreads();
  float* obuf = (float*)&P_l[0][0];
  if (w == 0 && l < 16) {
    lfin[li] = 1.f / l0;
    lfin[16 + li] = 1.f / l1;
    float* mp0 = ml + ((size_t)plane * 512 + i0 + li) * 2;
    mp0[0] = m0; mp0[1] = l0;
    float* mp1 = ml + ((size_t)plane * 512 + i0 + 16 + li) * 2;
    mp1[0] = m1; mp1[1] = l1;
  }
#pragma unroll
  for (int r = 0; r < 4; ++r)
    obuf[(itw * 16 + li) * 68 + dgw * 16 + lq * 4 + r] = oacc[r];
  __syncthreads();
  {
    const int iloc = tid >> 4, dq = tid & 15;
    const float rli = lfin[iloc];
    f32x4 o = *(f32x4*)&obuf[iloc * 68 + dq * 4];
    bhalf4 ov;
#pragma unroll
    for (int r = 0; r < 4; ++r) ov[r] = (__bf16)(o[r] * rli);
    *(bhalf4*)(vecb + ((size_t)(i0 + iloc) * 4 + b) * 512 + n * 64 + dq * 4) = ov;
  }
}

// ---------------------------------------------------------------------------
// am_v4: waves <-> planes. Grid (16 tb x 32 i-blocks x 4 b) = 2048 blocks,
// 512 thr. Wave w handles plane n=w end-to-end: BD into private bdl[w] slice
// (no block barriers), AC, scores, exp; cross-plane sum via LDS atomicAdd
// into accum[16][133] (pad -> ~2-way). Two __syncthreads total.
// ---------------------------------------------------------------------------
__global__ __launch_bounds__(512, 4) void am_v4(
    const __bf16* __restrict__ qup, const __bf16* __restrict__ qvp,
    const __bf16* __restrict__ kvb, const __bf16* __restrict__ relb,
    const float* __restrict__ indice, const float* __restrict__ ml,
    float* __restrict__ am_p)
{
  __shared__ __bf16 bdl[8][144][19];
  __shared__ float accum[16][133];

  const int bid = blockIdx.x;
  const int wrk = ((bid & 7) << 8) + (bid >> 3);   // XCD-contiguous
  const int b  = wrk >> 9;
  const int iy = (wrk >> 4) & 31;
  const int bx = wrk & 15;
  const int tb = bx << 7, i0 = iy << 4;
  const int tid = threadIdx.x;
  const int w = tid >> 6, l = tid & 63;
  const int li = l & 15, lq = l >> 4;
  float* outb = am_p + (size_t)b * 1048576;

  if (tb > 1536 + i0 + 15) {   // fully masked slice
#pragma unroll
    for (int c = 0; c < 4; ++c) {
      const int e = (c << 9) + tid;
      const int iloc = e >> 7, tl = e & 127;
      outb[(size_t)(i0 + iloc) * 2048 + tb + tl] = 0.f;
    }
    return;
  }

  const int rb = tb + 496 - i0;
  const int p = b * 8 + w;

  for (int f = tid; f < 2128; f += 512) ((float*)accum)[f] = 0.f;

  // Q fragments (pre-biased, pre-scaled)
  const __bf16* qpp = qup + ((size_t)p * 512 + i0 + li) * 64;
  const __bf16* qvv = qvp + ((size_t)p * 512 + i0 + li) * 64;
  bhalf8 qu0 = *(const bhalf8*)(qpp + lq * 8);
  bhalf8 qu1 = *(const bhalf8*)(qpp + 32 + lq * 8);
  bhalf8 qv0 = *(const bhalf8*)(qvv + lq * 8);
  bhalf8 qv1 = *(const bhalf8*)(qvv + 32 + lq * 8);
  const float* gp = indice + ((size_t)(i0 + li) * 4 + b) * 4;
  const float g0 = gp[0], g1 = gp[1], g2 = gp[2], g3 = gp[3];
  const float* mp = ml + ((size_t)p * 512 + i0 + li) * 2;
  const float mrow = mp[0];
  const float rl = 1.f / mp[1];
  __syncthreads();   // accum zeroed

  // BD: 9 r-subtiles into this wave's private bdl slice
#pragma unroll
  for (int rs = 0; rs < 9; ++rs) {
    int row = rb + (rs << 4) + li;
    row = row > 2047 ? 2047 : row;
    const __bf16* rp = relb + ((size_t)row * 4 + b) * 512 + (w << 6);
    bhalf8 a0 = *(const bhalf8*)(rp + lq * 8);
    bhalf8 a1 = *(const bhalf8*)(rp + 32 + lq * 8);
    f32x4 c = {0.f, 0.f, 0.f, 0.f};
    c = MFMA16(a0, qv0, c);
    c = MFMA16(a1, qv1, c);
#pragma unroll
    for (int r = 0; r < 4; ++r) {
      const int rrow = (rs << 4) + (lq << 2) + r;
      int rk = (rb + rrow) >> 9; rk = rk > 3 ? 3 : rk;
      const float gk = rk == 0 ? g0 : (rk == 1 ? g1 : (rk == 2 ? g2 : g3));
      bdl[w][rrow][li] = (__bf16)(c[r] * gk);
    }
  }
  // AC + scores + accumulate
#pragma unroll
  for (int ts = 0; ts < 8; ++ts) {
    const __bf16* kp = kvb + ((size_t)(tb + (ts << 4) + li) * 4 + b) * 1024 + (w << 6);
    bhalf8 a0 = *(const bhalf8*)(kp + lq * 8);
    bhalf8 a1 = *(const bhalf8*)(kp + 32 + lq * 8);
    f32x4 s = {0.f, 0.f, 0.f, 0.f};
    s = MFMA16(a0, qu0, s);
    s = MFMA16(a1, qu1, s);
#pragma unroll
    for (int r = 0; r < 4; ++r) {
      const int tl = (ts << 4) + (lq << 2) + r;
      const int t = tb + tl;
      if (t <= 1536 + i0 + li) {
        const float bdv = (float)bdl[w][tl + 15 - li][li];
        const float gk = (t >> 9) == 0 ? g0 : ((t >> 9) == 1 ? g1 : ((t >> 9) == 2 ? g2 : g3));
        const float sc = s[r] * gk + bdv;
        atomicAdd(&accum[li][tl], __expf(sc - mrow) * rl);
      }
    }
  }
  __syncthreads();   // all planes accumulated
#pragma unroll
  for (int c = 0; c < 4; ++c) {
    const int e = (c << 9) + tid;
    const int iloc = e >> 7, tl = e & 127;
    outb[(size_t)(i0 + iloc) * 2048 + tb + tl] = accum[iloc][tl] * 0.03125f;
  }
}

// ---------------------------------------------------------------------------
// am = sum of 4 per-b partials
// ---------------------------------------------------------------------------
__global__ __launch_bounds__(256) void am_reduce(const float* __restrict__ am_p,
                                                 float* __restrict__ am)
{
  const size_t i = ((size_t)blockIdx.x * 256 + threadIdx.x) * 4;
  f32x4 v = *(const f32x4*)(am_p + i);
  v += *(const f32x4*)(am_p + 1048576 + i);
  v += *(const f32x4*)(am_p + 2097152 + i);
  v += *(const f32x4*)(am_p + 3145728 + i);
  *(f32x4*)(am + i) = v;
}

// ---------------------------------------------------------------------------
// Residual + LayerNorm
// ---------------------------------------------------------------------------
__global__ __launch_bounds__(256) void ln_f32(
    const float* __restrict__ x, const float* __restrict__ ao,
    const float* __restrict__ g, const float* __restrict__ bb,
    float* __restrict__ out)
{
  const int row = blockIdx.x;
  const int tid = threadIdx.x;
  const size_t base = (size_t)row * 512;
  const float y0 = x[base + tid] + ao[base + tid];
  const float y1 = x[base + 256 + tid] + ao[base + 256 + tid];
  float s  = y0 + y1;
  float ss = y0 * y0 + y1 * y1;
#pragma unroll
  for (int off = 32; off > 0; off >>= 1) {
    s  += __shfl_xor(s, off);
    ss += __shfl_xor(ss, off);
  }
  __shared__ float sred[4], ssred[4], stat[2];
  const int w = tid >> 6;
  if ((tid & 63) == 0) { sred[w] = s; ssred[w] = ss; }
  __syncthreads();
  if (tid == 0) {
    const float S  = sred[0] + sred[1] + sred[2] + sred[3];
    const float SS = ssred[0] + ssred[1] + ssred[2] + ssred[3];
    const float mu = S * (1.f / 512.f);
    const float var = SS * (1.f / 512.f) - mu * mu;
    stat[0] = mu;
    stat[1] = rsqrtf(var + 1e-5f);
  }
  __syncthreads();
  const float mu = stat[0], rs = stat[1];
  out[base + tid]       = (y0 - mu) * rs * g[tid] + bb[tid];
  out[base + 256 + tid] = (y1 - mu) * rs * g[256 + tid] + bb[256 + tid];
}

// ---------------------------------------------------------------------------
// Launch. ws layout (bf16 elem offsets):
//   cb    @ 0          4,194,304  (concat; -> vtb; -> am_p lower half; -> aof)
//   posb  @ 4,194,304  4,194,304  (pos; -> am_p upper half)
//   kvb   @ 8,388,608  8,388,608
//   relb  @ 16,777,216 4,194,304
//   qup   @ 20,971,520 1,048,576
//   qvp   @ 22,020,096 1,048,576
//   vecb  @ 23,068,672 1,048,576
//   wqt   @ 24,117,248 262,144 / wkvt 524,288 / wrelt 262,144 / wot 262,144
//   ml f32 @ byte 50,855,936 (128 KB)  -> total ~51.0 MB
// ---------------------------------------------------------------------------
extern "C" void kernel_launch(void* const* d_in, const int* in_sizes, int n_in,
                              void* d_out, int out_size, void* d_ws, size_t ws_size,
                              hipStream_t stream)
{
  (void)in_sizes; (void)n_in; (void)out_size; (void)ws_size;
  const float* x      = (const float*)d_in[0];
  const float* memory = (const float*)d_in[1];
  const float* pos    = (const float*)d_in[2];
  const float* pbu    = (const float*)d_in[3];
  const float* pbv    = (const float*)d_in[4];
  const float* indice = (const float*)d_in[6];
  const float* W_q    = (const float*)d_in[7];
  const float* W_kv   = (const float*)d_in[8];
  const float* W_rel  = (const float*)d_in[9];
  const float* W_o    = (const float*)d_in[10];
  const float* ln_g   = (const float*)d_in[11];
  const float* ln_b   = (const float*)d_in[12];

  float* out = (float*)d_out;
  float* am  = out + 1048576;

  __bf16* cb    = (__bf16*)d_ws;
  __bf16* posb  = cb + 4194304;
  __bf16* kvb   = posb + 4194304;
  __bf16* relb  = kvb + 8388608;
  __bf16* qup   = relb + 4194304;
  __bf16* qvp   = qup + 1048576;
  __bf16* vecb  = qvp + 1048576;
  __bf16* wqt   = vecb + 1048576;
  __bf16* wkvt  = wqt + 262144;
  __bf16* wrelt = wkvt + 524288;
  __bf16* wot   = wrelt + 262144;
  float*  ml    = (float*)(wot + 262144);
  __bf16* xb    = cb + 3145728;          // x rows start at concat row 6144
  __bf16* vtb   = cb;                    // reuses cb after kv GEMM
  float*  am_p  = (float*)d_ws;          // 16MB over cb+posb after attn
  float*  aof   = (float*)d_ws;          // 4MB over cb after am_reduce

  cast_bf16<<<3072, 256, 0, stream>>>(memory, cb, 786432);
  cast_bf16<<<1024, 256, 0, stream>>>(x, xb, 262144);
  cast_bf16<<<4096, 256, 0, stream>>>(pos, posb, 1048576);
  transcast<<<dim3(8, 128), 256, 0, stream>>>(W_q,   wqt,   512, 512);
  transcast<<<dim3(8, 256), 256, 0, stream>>>(W_kv,  wkvt,  512, 1024);
  transcast<<<dim3(8, 128), 256, 0, stream>>>(W_rel, wrelt, 512, 512);
  transcast<<<dim3(8, 128), 256, 0, stream>>>(W_o,   wot,   512, 512);

  gemm_bf16<2><<<dim3(16, 4), 256, 0, stream>>>(xb, wqt, (void*)qup, 2048, 512, 512,
                                                pbu, pbv, qup, qvp);
  gemm_bf16<0><<<dim3(64, 8), 256, 0, stream>>>(cb, wkvt, kvb, 8192, 1024, 512,
                                                nullptr, nullptr, nullptr, nullptr);
  gemm_bf16<0><<<dim3(64, 4), 256, 0, stream>>>(posb, wrelt, relb, 8192, 512, 512,
                                                nullptr, nullptr, nullptr, nullptr);

  vtrans<<<dim3(32, 32), 256, 0, stream>>>(kvb, vtb);

  attn_v3<<<512, 512, 0, stream>>>(qup, qvp, kvb, relb, vtb, indice, vecb, ml);

  am_v4<<<2048, 512, 0, stream>>>(qup, qvp, kvb, relb, indice, ml, am_p);
  am_reduce<<<1024, 256, 0, stream>>>(am_p, am);

  gemm_bf16<1><<<dim3(16, 4), 256, 0, stream>>>(vecb, wot, aof, 2048, 512, 512,
                                                nullptr, nullptr, nullptr, nullptr);
  ln_f32<<<2048, 256, 0, stream>>>(x, aof, ln_g, ln_b, out);
}

// Round 5
// 376.756 us; speedup vs baseline: 1.2443x; 1.2443x over previous
//
#include <hip/hip_runtime.h>
#include <hip/hip_bf16.h>
#include <math.h>

typedef __bf16 bhalf8 __attribute__((ext_vector_type(8)));
typedef __bf16 bhalf4 __attribute__((ext_vector_type(4)));
typedef float  f32x4  __attribute__((ext_vector_type(4)));

#define MFMA16(a, b, c) __builtin_amdgcn_mfma_f32_16x16x32_bf16(a, b, c, 0, 0, 0)

// ---------------------------------------------------------------------------
// cast f32 -> bf16
// ---------------------------------------------------------------------------
__global__ __launch_bounds__(256) void cast_bf16(const float* __restrict__ in,
                                                 __bf16* __restrict__ out, int n4)
{
  const int i = blockIdx.x * 256 + threadIdx.x;
  if (i < n4) {
    float4 v = ((const float4*)in)[i];
    bhalf4 o;
    o[0] = (__bf16)v.x; o[1] = (__bf16)v.y; o[2] = (__bf16)v.z; o[3] = (__bf16)v.w;
    ((bhalf4*)out)[i] = o;
  }
}

// ---------------------------------------------------------------------------
// transpose+cast: W [K][N] f32 -> Wt [N][K] bf16
// ---------------------------------------------------------------------------
__global__ __launch_bounds__(256) void transcast(const float* __restrict__ W,
                                                 __bf16* __restrict__ Wt, int K, int N)
{
  const int k = blockIdx.x * 64 + (threadIdx.x & 63);
  const int n = blockIdx.y * 4 + (threadIdx.x >> 6);
  Wt[(size_t)n * K + k] = (__bf16)W[(size_t)k * N + n];
}

// ---------------------------------------------------------------------------
// bf16 MFMA GEMM: C[M][N] = A[M][K] @ Bt[N][K]^T
// OUT_MODE 0: bf16 C; 1: f32 C; 2: attention-Q epilogue -> qup/qvp
// ---------------------------------------------------------------------------
template <int OUT_MODE>
__global__ __launch_bounds__(256) void gemm_bf16(
    const __bf16* __restrict__ A, const __bf16* __restrict__ Bt,
    void* __restrict__ C, int M, int N, int K,
    const float* __restrict__ pbu, const float* __restrict__ pbv,
    __bf16* __restrict__ qup, __bf16* __restrict__ qvp)
{
  __shared__ __bf16 a_lds[128][40];
  __shared__ __bf16 b_lds[128][40];
  const int m0 = blockIdx.x * 128;
  const int n0 = blockIdx.y * 128;
  const int tid = threadIdx.x;
  const int w = tid >> 6, l = tid & 63;
  const int wn = (w >> 1) * 64, wm = (w & 1) * 64;
  const int li = l & 15, lq = l >> 4;
  const int lk = lq << 3;

  f32x4 acc[4][4] = {};

  for (int k0 = 0; k0 < K; k0 += 32) {
    __syncthreads();
#pragma unroll
    for (int c = 0; c < 2; ++c) {
      const int chunk = c * 256 + tid;
      const int row = chunk >> 2, kc = (chunk & 3) << 3;
      *(bhalf8*)&a_lds[row][kc] = *(const bhalf8*)(A + (size_t)(m0 + row) * K + k0 + kc);
      *(bhalf8*)&b_lds[row][kc] = *(const bhalf8*)(Bt + (size_t)(n0 + row) * K + k0 + kc);
    }
    __syncthreads();
    bhalf8 af[4], bf_[4];
#pragma unroll
    for (int s = 0; s < 4; ++s) {
      af[s]  = *(const bhalf8*)&b_lds[wn + s * 16 + li][lk];
      bf_[s] = *(const bhalf8*)&a_lds[wm + s * 16 + li][lk];
    }
#pragma unroll
    for (int ns = 0; ns < 4; ++ns)
#pragma unroll
      for (int ms = 0; ms < 4; ++ms)
        acc[ns][ms] = MFMA16(af[ns], bf_[ms], acc[ns][ms]);
  }

  const int lr = lq << 2;
#pragma unroll
  for (int ms = 0; ms < 4; ++ms) {
    const int m = m0 + wm + ms * 16 + li;
#pragma unroll
    for (int ns = 0; ns < 4; ++ns) {
      const int n = n0 + wn + ns * 16 + lr;
      if (OUT_MODE == 1) {
        *(f32x4*)((float*)C + (size_t)m * N + n) = acc[ns][ms];
      } else if (OUT_MODE == 0) {
        bhalf4 pk;
#pragma unroll
        for (int r = 0; r < 4; ++r) pk[r] = (__bf16)acc[ns][ms][r];
        *(bhalf4*)((__bf16*)C + (size_t)m * N + n) = pk;
      } else {
        const int i = m >> 2, bb = m & 3, hd = n >> 6;
        float4 u4 = *(const float4*)(pbu + n);
        float4 v4 = *(const float4*)(pbv + n);
        const size_t off = (((size_t)bb * 8 + hd) * 512 + i) * 64 + (n & 63);
        bhalf4 pu, pv;
        pu[0] = (__bf16)((acc[ns][ms][0] + u4.x) * 0.125f);
        pu[1] = (__bf16)((acc[ns][ms][1] + u4.y) * 0.125f);
        pu[2] = (__bf16)((acc[ns][ms][2] + u4.z) * 0.125f);
        pu[3] = (__bf16)((acc[ns][ms][3] + u4.w) * 0.125f);
        pv[0] = (__bf16)((acc[ns][ms][0] + v4.x) * 0.125f);
        pv[1] = (__bf16)((acc[ns][ms][1] + v4.y) * 0.125f);
        pv[2] = (__bf16)((acc[ns][ms][2] + v4.z) * 0.125f);
        pv[3] = (__bf16)((acc[ns][ms][3] + v4.w) * 0.125f);
        *(bhalf4*)(qup + off) = pu;
        *(bhalf4*)(qvp + off) = pv;
      }
    }
  }
}

// ---------------------------------------------------------------------------
// V transpose: vtb[plane][d][t]
// ---------------------------------------------------------------------------
__global__ __launch_bounds__(256) void vtrans(const __bf16* __restrict__ kvb,
                                              __bf16* __restrict__ vtb)
{
  __shared__ __bf16 T2[64][72];
  const int t0 = blockIdx.x * 64;
  const int p = blockIdx.y;
  const int b = p >> 3, n = p & 7;
  const int tid = threadIdx.x;
#pragma unroll
  for (int c = 0; c < 2; ++c) {
    const int e = c * 256 + tid;
    const int tl = e >> 3, d8 = (e & 7) << 3;
    bhalf8 v8 = *(const bhalf8*)(kvb + ((size_t)(t0 + tl) * 4 + b) * 1024 + 512 + n * 64 + d8);
#pragma unroll
    for (int j = 0; j < 8; ++j) T2[d8 + j][tl] = v8[j];
  }
  __syncthreads();
#pragma unroll
  for (int c = 0; c < 2; ++c) {
    const int e = c * 256 + tid;
    const int d = e >> 3, t8 = (e & 7) << 3;
    bhalf8 v = *(const bhalf8*)&T2[d][t8];
    *(bhalf8*)(vtb + ((size_t)p * 64 + d) * 2048 + t0 + t8) = v;
  }
}

// ---------------------------------------------------------------------------
// Fused flash attention (unchanged from round 4).
// ---------------------------------------------------------------------------
__global__ __launch_bounds__(512, 4) void attn_v3(
    const __bf16* __restrict__ qup, const __bf16* __restrict__ qvp,
    const __bf16* __restrict__ kvb, const __bf16* __restrict__ relb,
    const __bf16* __restrict__ vtb, const float* __restrict__ indice,
    __bf16* __restrict__ vecb, float* __restrict__ ml)
{
  __shared__ __align__(16) __bf16 P_l[32][136];
  __shared__ __align__(16) __bf16 bdl[160][33];
  __shared__ float red0[8][33];
  __shared__ float red1[8][33];
  __shared__ float lfin[32];

  const int bid = blockIdx.x;
  const int wrk = ((bid & 7) << 6) + (bid >> 3);
  const int plane = wrk >> 4;
  const int i0 = (wrk & 15) << 5;
  const int b = plane >> 3, n = plane & 7;
  const int tid = threadIdx.x;
  const int w = tid >> 6;
  const int l = tid & 63;
  const int li = l & 15;
  const int lq = l >> 4;

  const __bf16* kbase = kvb + (size_t)b * 1024 + n * 64;
  const __bf16* rbase = relb + (size_t)b * 512 + n * 64;
  const __bf16* vbase = vtb + (size_t)plane * 131072;

  bhalf8 qu[2][2], qv[2][2];
  float g[2][4];
#pragma unroll
  for (int it = 0; it < 2; ++it) {
    const int i = i0 + it * 16 + li;
    const float* gp = indice + ((size_t)i * 4 + b) * 4;
    g[it][0] = gp[0]; g[it][1] = gp[1]; g[it][2] = gp[2]; g[it][3] = gp[3];
    const __bf16* qp = qup + ((size_t)plane * 512 + i) * 64;
    const __bf16* qq = qvp + ((size_t)plane * 512 + i) * 64;
    qu[it][0] = *(const bhalf8*)(qp + lq * 8);
    qu[it][1] = *(const bhalf8*)(qp + 32 + lq * 8);
    qv[it][0] = *(const bhalf8*)(qq + lq * 8);
    qv[it][1] = *(const bhalf8*)(qq + 32 + lq * 8);
  }

  float m0 = -1e30f, m1 = -1e30f, l0 = 0.f, l1 = 0.f;
  f32x4 oacc = {0.f, 0.f, 0.f, 0.f};
  const int dgw = w >> 1, itw = w & 1;
  const int nt = ((1536 + i0 + 31) >> 7) + 1;

  for (int tile = 0; tile < nt; ++tile) {
    const int tb = tile << 7;
    const int rb = tb + 480 - i0;

    // ---- BD ----
#pragma unroll
    for (int ri = 0; ri < 2; ++ri) {
      const int rs = w + ri * 8;
      if (ri == 0 || rs < 10) {
        int row = rb + rs * 16 + li;
        row = row > 2047 ? 2047 : row;
        const __bf16* rp = rbase + (size_t)row * 2048;
        bhalf8 a0 = *(const bhalf8*)(rp + lq * 8);
        bhalf8 a1 = *(const bhalf8*)(rp + 32 + lq * 8);
#pragma unroll
        for (int it = 0; it < 2; ++it) {
          f32x4 c = {0.f, 0.f, 0.f, 0.f};
          c = MFMA16(a0, qv[it][0], c);
          c = MFMA16(a1, qv[it][1], c);
#pragma unroll
          for (int r = 0; r < 4; ++r) {
            const int rowl = rs * 16 + lq * 4 + r;
            int rk = (rb + rowl) >> 9; rk = rk > 3 ? 3 : rk;
            bdl[rowl][it * 16 + li] = (__bf16)(c[r] * g[it][rk]);
          }
        }
      }
    }
    // ---- AC ----
    f32x4 s[2];
    {
      const __bf16* kp = kbase + (size_t)(tb + w * 16 + li) * 4096;
      bhalf8 a0 = *(const bhalf8*)(kp + lq * 8);
      bhalf8 a1 = *(const bhalf8*)(kp + 32 + lq * 8);
#pragma unroll
      for (int it = 0; it < 2; ++it) {
        f32x4 c = {0.f, 0.f, 0.f, 0.f};
        c = MFMA16(a0, qu[it][0], c);
        c = MFMA16(a1, qu[it][1], c);
        s[it] = c;
      }
    }
    __syncthreads();   // bd visible

    float sv[2][4];
    float tmax[2] = {-1e30f, -1e30f};
#pragma unroll
    for (int it = 0; it < 2; ++it) {
      const int i = i0 + it * 16 + li;
#pragma unroll
      for (int r = 0; r < 4; ++r) {
        const int tl = w * 16 + lq * 4 + r;
        const int t = tb + tl;
        float sc = -1e30f;
        if (t <= 1536 + i) {
          const float bdv = (float)bdl[tl + 31 - it * 16 - li][it * 16 + li];
          sc = s[it][r] * g[it][t >> 9] + bdv;
        }
        sv[it][r] = sc;
        tmax[it] = fmaxf(tmax[it], sc);
      }
    }
    tmax[0] = fmaxf(tmax[0], __shfl_xor(tmax[0], 16));
    tmax[0] = fmaxf(tmax[0], __shfl_xor(tmax[0], 32));
    tmax[1] = fmaxf(tmax[1], __shfl_xor(tmax[1], 16));
    tmax[1] = fmaxf(tmax[1], __shfl_xor(tmax[1], 32));
    if (l < 16) { red0[w][li] = tmax[0]; red0[w][16 + li] = tmax[1]; }
    __syncthreads();

    float mn[2], scl[2];
#pragma unroll
    for (int it = 0; it < 2; ++it) {
      const int ic = it * 16 + li;
      float mt = red0[0][ic];
#pragma unroll
      for (int ww = 1; ww < 8; ++ww) mt = fmaxf(mt, red0[ww][ic]);
      const float mo = it ? m1 : m0;
      mn[it] = fmaxf(mo, mt);
      scl[it] = __expf(mo - mn[it]);
    }
    float ps[2] = {0.f, 0.f};
#pragma unroll
    for (int it = 0; it < 2; ++it) {
      bhalf4 pk;
#pragma unroll
      for (int r = 0; r < 4; ++r) {
        const float p = __expf(sv[it][r] - mn[it]);
        ps[it] += p;
        pk[r] = (__bf16)p;
      }
      *(bhalf4*)&P_l[it * 16 + li][w * 16 + lq * 4] = pk;
    }
    ps[0] += __shfl_xor(ps[0], 16); ps[0] += __shfl_xor(ps[0], 32);
    ps[1] += __shfl_xor(ps[1], 16); ps[1] += __shfl_xor(ps[1], 32);
    if (l < 16) { red1[w][li] = ps[0]; red1[w][16 + li] = ps[1]; }
    __syncthreads();

    {
      float ls0 = 0.f, ls1 = 0.f;
#pragma unroll
      for (int ww = 0; ww < 8; ++ww) { ls0 += red1[ww][li]; ls1 += red1[ww][16 + li]; }
      l0 = l0 * scl[0] + ls0; m0 = mn[0];
      l1 = l1 * scl[1] + ls1; m1 = mn[1];
    }
    // ---- PV ----
    oacc *= scl[itw];
    {
      const __bf16* vp = vbase + (size_t)(dgw * 16 + li) * 2048 + tb;
#pragma unroll
      for (int kt = 0; kt < 4; ++kt) {
        bhalf8 af = *(const bhalf8*)(vp + kt * 32 + lq * 8);
        bhalf8 bf_ = *(const bhalf8*)&P_l[itw * 16 + li][kt * 32 + lq * 8];
        oacc = MFMA16(af, bf_, oacc);
      }
    }
  }

  __syncthreads();
  float* obuf = (float*)&P_l[0][0];
  if (w == 0 && l < 16) {
    lfin[li] = 1.f / l0;
    lfin[16 + li] = 1.f / l1;
    float* mp0 = ml + ((size_t)plane * 512 + i0 + li) * 2;
    mp0[0] = m0; mp0[1] = l0;
    float* mp1 = ml + ((size_t)plane * 512 + i0 + 16 + li) * 2;
    mp1[0] = m1; mp1[1] = l1;
  }
#pragma unroll
  for (int r = 0; r < 4; ++r)
    obuf[(itw * 16 + li) * 68 + dgw * 16 + lq * 4 + r] = oacc[r];
  __syncthreads();
  {
    const int iloc = tid >> 4, dq = tid & 15;
    const float rli = lfin[iloc];
    f32x4 o = *(f32x4*)&obuf[iloc * 68 + dq * 4];
    bhalf4 ov;
#pragma unroll
    for (int r = 0; r < 4; ++r) ov[r] = (__bf16)(o[r] * rli);
    *(bhalf4*)(vecb + ((size_t)(i0 + iloc) * 4 + b) * 512 + n * 64 + dq * 4) = ov;
  }
}

// ---------------------------------------------------------------------------
// am_v5: proven am_v3 structure (block = (tb, 32-row i-block, b); serial loop
// over 8 planes) with: qup/qvp pre-biased/pre-scaled Q (no per-plane Q-prep
// VALU), gates hoisted out of plane loop, double-buffered bdl (ONE barrier
// per plane), pad 34 (17-dword stride).
// ---------------------------------------------------------------------------
__global__ __launch_bounds__(512, 4) void am_v5(
    const __bf16* __restrict__ qup, const __bf16* __restrict__ qvp,
    const __bf16* __restrict__ kvb, const __bf16* __restrict__ relb,
    const float* __restrict__ indice, const float* __restrict__ ml,
    float* __restrict__ am_p)
{
  __shared__ __align__(16) __bf16 bdl[2][160][34];
  __shared__ __align__(16) float Lt[32][132];

  const int bid = blockIdx.x;
  const int wrk = ((bid & 7) << 7) + (bid >> 3);   // 1024 % 8 == 0 -> bijective
  const int bx = wrk & 15;
  const int by = (wrk >> 4) & 15;
  const int b  = wrk >> 8;
  const int tb = bx << 7, i0 = by << 5;
  const int tid = threadIdx.x;
  const int w = tid >> 6, l = tid & 63;
  const int li = l & 15, lq = l >> 4;
  float* outb = am_p + (size_t)b * 1048576;

  if (tb > 1536 + i0 + 31) {   // fully masked slice -> zeros
#pragma unroll
    for (int c = 0; c < 2; ++c) {
      const int e = c * 512 + tid;
      const int iloc = e >> 5, tq = e & 31;
      f32x4 z = {0.f, 0.f, 0.f, 0.f};
      *(f32x4*)(outb + (size_t)(i0 + iloc) * 2048 + tb + tq * 4) = z;
    }
    return;
  }

  const int rb = tb + 480 - i0;
  float acc[2][4] = {};

  // hoisted gates (b-invariant across planes)
  float g[2][4];
#pragma unroll
  for (int it = 0; it < 2; ++it) {
    const float* gp = indice + ((size_t)(i0 + it * 16 + li) * 4 + b) * 4;
    g[it][0] = gp[0]; g[it][1] = gp[1]; g[it][2] = gp[2]; g[it][3] = gp[3];
  }

  for (int nn = 0; nn < 8; ++nn) {
    const int p = b * 8 + nn;
    const int buf = nn & 1;

    // Q fragments (pre-biased, pre-scaled) + per-plane m,l
    bhalf8 qu[2][2], qv[2][2];
    float mrow[2], rl[2];
#pragma unroll
    for (int it = 0; it < 2; ++it) {
      const int i = i0 + it * 16 + li;
      const __bf16* qp = qup + ((size_t)p * 512 + i) * 64;
      const __bf16* qq = qvp + ((size_t)p * 512 + i) * 64;
      qu[it][0] = *(const bhalf8*)(qp + lq * 8);
      qu[it][1] = *(const bhalf8*)(qp + 32 + lq * 8);
      qv[it][0] = *(const bhalf8*)(qq + lq * 8);
      qv[it][1] = *(const bhalf8*)(qq + 32 + lq * 8);
      const float* mp = ml + ((size_t)p * 512 + i) * 2;
      mrow[it] = mp[0];
      rl[it] = 1.f / mp[1];
    }

    // BD into bdl[buf]
#pragma unroll
    for (int ri = 0; ri < 2; ++ri) {
      const int rs = w + ri * 8;
      if (ri == 0 || rs < 10) {
        int row = rb + rs * 16 + li;
        row = row > 2047 ? 2047 : row;
        const __bf16* rp = relb + ((size_t)row * 4 + b) * 512 + nn * 64;
        bhalf8 a0 = *(const bhalf8*)(rp + lq * 8);
        bhalf8 a1 = *(const bhalf8*)(rp + 32 + lq * 8);
#pragma unroll
        for (int it = 0; it < 2; ++it) {
          f32x4 c = {0.f, 0.f, 0.f, 0.f};
          c = MFMA16(a0, qv[it][0], c);
          c = MFMA16(a1, qv[it][1], c);
#pragma unroll
          for (int r = 0; r < 4; ++r) {
            const int rowl = rs * 16 + lq * 4 + r;
            int rk = (rb + rowl) >> 9; rk = rk > 3 ? 3 : rk;
            bdl[buf][rowl][it * 16 + li] = (__bf16)(c[r] * g[it][rk]);
          }
        }
      }
    }
    __syncthreads();   // bdl[buf] visible; bdl[buf^1] reads of plane nn-1 done

    // AC + scores
    f32x4 s[2];
    {
      const __bf16* kp = kvb + ((size_t)(tb + w * 16 + li) * 4 + b) * 1024 + nn * 64;
      bhalf8 a0 = *(const bhalf8*)(kp + lq * 8);
      bhalf8 a1 = *(const bhalf8*)(kp + 32 + lq * 8);
#pragma unroll
      for (int it = 0; it < 2; ++it) {
        f32x4 c = {0.f, 0.f, 0.f, 0.f};
        c = MFMA16(a0, qu[it][0], c);
        c = MFMA16(a1, qu[it][1], c);
        s[it] = c;
      }
    }
#pragma unroll
    for (int it = 0; it < 2; ++it) {
      const int i = i0 + it * 16 + li;
#pragma unroll
      for (int r = 0; r < 4; ++r) {
        const int tl = w * 16 + lq * 4 + r;
        const int t = tb + tl;
        if (t <= 1536 + i) {
          const float bdv = (float)bdl[buf][tl + 31 - it * 16 - li][it * 16 + li];
          const float sc = s[it][r] * g[it][t >> 9] + bdv;
          acc[it][r] += __expf(sc - mrow[it]) * rl[it];
        }
      }
    }
    // no trailing barrier: next plane writes bdl[buf^1]; rewrite of bdl[buf]
    // happens after the NEXT sync -> one full barrier between read & rewrite.
  }

  // coalesced writeback via Lt
#pragma unroll
  for (int it = 0; it < 2; ++it)
#pragma unroll
    for (int r = 0; r < 4; ++r)
      Lt[it * 16 + li][w * 16 + lq * 4 + r] = acc[it][r] * 0.03125f;
  __syncthreads();
#pragma unroll
  for (int c = 0; c < 2; ++c) {
    const int e = c * 512 + tid;
    const int iloc = e >> 5, tq = e & 31;
    f32x4 v = *(f32x4*)&Lt[iloc][tq * 4];
    *(f32x4*)(outb + (size_t)(i0 + iloc) * 2048 + tb + tq * 4) = v;
  }
}

// ---------------------------------------------------------------------------
// am = sum of 4 per-b partials
// ---------------------------------------------------------------------------
__global__ __launch_bounds__(256) void am_reduce(const float* __restrict__ am_p,
                                                 float* __restrict__ am)
{
  const size_t i = ((size_t)blockIdx.x * 256 + threadIdx.x) * 4;
  f32x4 v = *(const f32x4*)(am_p + i);
  v += *(const f32x4*)(am_p + 1048576 + i);
  v += *(const f32x4*)(am_p + 2097152 + i);
  v += *(const f32x4*)(am_p + 3145728 + i);
  *(f32x4*)(am + i) = v;
}

// ---------------------------------------------------------------------------
// Residual + LayerNorm
// ---------------------------------------------------------------------------
__global__ __launch_bounds__(256) void ln_f32(
    const float* __restrict__ x, const float* __restrict__ ao,
    const float* __restrict__ g, const float* __restrict__ bb,
    float* __restrict__ out)
{
  const int row = blockIdx.x;
  const int tid = threadIdx.x;
  const size_t base = (size_t)row * 512;
  const float y0 = x[base + tid] + ao[base + tid];
  const float y1 = x[base + 256 + tid] + ao[base + 256 + tid];
  float s  = y0 + y1;
  float ss = y0 * y0 + y1 * y1;
#pragma unroll
  for (int off = 32; off > 0; off >>= 1) {
    s  += __shfl_xor(s, off);
    ss += __shfl_xor(ss, off);
  }
  __shared__ float sred[4], ssred[4], stat[2];
  const int w = tid >> 6;
  if ((tid & 63) == 0) { sred[w] = s; ssred[w] = ss; }
  __syncthreads();
  if (tid == 0) {
    const float S  = sred[0] + sred[1] + sred[2] + sred[3];
    const float SS = ssred[0] + ssred[1] + ssred[2] + ssred[3];
    const float mu = S * (1.f / 512.f);
    const float var = SS * (1.f / 512.f) - mu * mu;
    stat[0] = mu;
    stat[1] = rsqrtf(var + 1e-5f);
  }
  __syncthreads();
  const float mu = stat[0], rs = stat[1];
  out[base + tid]       = (y0 - mu) * rs * g[tid] + bb[tid];
  out[base + 256 + tid] = (y1 - mu) * rs * g[256 + tid] + bb[256 + tid];
}

// ---------------------------------------------------------------------------
// Launch. ws layout identical to round 4 (~51 MB).
// ---------------------------------------------------------------------------
extern "C" void kernel_launch(void* const* d_in, const int* in_sizes, int n_in,
                              void* d_out, int out_size, void* d_ws, size_t ws_size,
                              hipStream_t stream)
{
  (void)in_sizes; (void)n_in; (void)out_size; (void)ws_size;
  const float* x      = (const float*)d_in[0];
  const float* memory = (const float*)d_in[1];
  const float* pos    = (const float*)d_in[2];
  const float* pbu    = (const float*)d_in[3];
  const float* pbv    = (const float*)d_in[4];
  const float* indice = (const float*)d_in[6];
  const float* W_q    = (const float*)d_in[7];
  const float* W_kv   = (const float*)d_in[8];
  const float* W_rel  = (const float*)d_in[9];
  const float* W_o    = (const float*)d_in[10];
  const float* ln_g   = (const float*)d_in[11];
  const float* ln_b   = (const float*)d_in[12];

  float* out = (float*)d_out;
  float* am  = out + 1048576;

  __bf16* cb    = (__bf16*)d_ws;
  __bf16* posb  = cb + 4194304;
  __bf16* kvb   = posb + 4194304;
  __bf16* relb  = kvb + 8388608;
  __bf16* qup   = relb + 4194304;
  __bf16* qvp   = qup + 1048576;
  __bf16* vecb  = qvp + 1048576;
  __bf16* wqt   = vecb + 1048576;
  __bf16* wkvt  = wqt + 262144;
  __bf16* wrelt = wkvt + 524288;
  __bf16* wot   = wrelt + 262144;
  float*  ml    = (float*)(wot + 262144);
  __bf16* xb    = cb + 3145728;          // x rows start at concat row 6144
  __bf16* vtb   = cb;                    // reuses cb after kv GEMM
  float*  am_p  = (float*)d_ws;          // 16MB over cb+posb after attn
  float*  aof   = (float*)d_ws;          // 4MB over cb after am_reduce

  cast_bf16<<<3072, 256, 0, stream>>>(memory, cb, 786432);
  cast_bf16<<<1024, 256, 0, stream>>>(x, xb, 262144);
  cast_bf16<<<4096, 256, 0, stream>>>(pos, posb, 1048576);
  transcast<<<dim3(8, 128), 256, 0, stream>>>(W_q,   wqt,   512, 512);
  transcast<<<dim3(8, 256), 256, 0, stream>>>(W_kv,  wkvt,  512, 1024);
  transcast<<<dim3(8, 128), 256, 0, stream>>>(W_rel, wrelt, 512, 512);
  transcast<<<dim3(8, 128), 256, 0, stream>>>(W_o,   wot,   512, 512);

  gemm_bf16<2><<<dim3(16, 4), 256, 0, stream>>>(xb, wqt, (void*)qup, 2048, 512, 512,
                                                pbu, pbv, qup, qvp);
  gemm_bf16<0><<<dim3(64, 8), 256, 0, stream>>>(cb, wkvt, kvb, 8192, 1024, 512,
                                                nullptr, nullptr, nullptr, nullptr);
  gemm_bf16<0><<<dim3(64, 4), 256, 0, stream>>>(posb, wrelt, relb, 8192, 512, 512,
                                                nullptr, nullptr, nullptr, nullptr);

  vtrans<<<dim3(32, 32), 256, 0, stream>>>(kvb, vtb);

  attn_v3<<<512, 512, 0, stream>>>(qup, qvp, kvb, relb, vtb, indice, vecb, ml);

  am_v5<<<1024, 512, 0, stream>>>(qup, qvp, kvb, relb, indice, ml, am_p);
  am_reduce<<<1024, 256, 0, stream>>>(am_p, am);

  gemm_bf16<1><<<dim3(16, 4), 256, 0, stream>>>(vecb, wot, aof, 2048, 512, 512,
                                                nullptr, nullptr, nullptr, nullptr);
  ln_f32<<<2048, 256, 0, stream>>>(x, aof, ln_g, ln_b, out);
}

// Round 6
// 301.624 us; speedup vs baseline: 1.5542x; 1.2491x over previous
//
#include <hip/hip_runtime.h>
#include <hip/hip_bf16.h>
#include <math.h>

typedef __bf16 bhalf8 __attribute__((ext_vector_type(8)));
typedef __bf16 bhalf4 __attribute__((ext_vector_type(4)));
typedef float  f32x4  __attribute__((ext_vector_type(4)));

#define MFMA16(a, b, c) __builtin_amdgcn_mfma_f32_16x16x32_bf16(a, b, c, 0, 0, 0)

// ---------------------------------------------------------------------------
// cast f32 -> bf16
// ---------------------------------------------------------------------------
__global__ __launch_bounds__(256) void cast_bf16(const float* __restrict__ in,
                                                 __bf16* __restrict__ out, int n4)
{
  const int i = blockIdx.x * 256 + threadIdx.x;
  if (i < n4) {
    float4 v = ((const float4*)in)[i];
    bhalf4 o;
    o[0] = (__bf16)v.x; o[1] = (__bf16)v.y; o[2] = (__bf16)v.z; o[3] = (__bf16)v.w;
    ((bhalf4*)out)[i] = o;
  }
}

// ---------------------------------------------------------------------------
// transpose+cast: W [K][N] f32 -> Wt [N][K] bf16
// ---------------------------------------------------------------------------
__global__ __launch_bounds__(256) void transcast(const float* __restrict__ W,
                                                 __bf16* __restrict__ Wt, int K, int N)
{
  const int k = blockIdx.x * 64 + (threadIdx.x & 63);
  const int n = blockIdx.y * 4 + (threadIdx.x >> 6);
  Wt[(size_t)n * K + k] = (__bf16)W[(size_t)k * N + n];
}

// ---------------------------------------------------------------------------
// bf16 MFMA GEMM: C[M][N] = A[M][K] @ Bt[N][K]^T
// OUT_MODE 0: bf16 C; 1: f32 C; 2: attention-Q epilogue -> qup/qvp
// ---------------------------------------------------------------------------
template <int OUT_MODE>
__global__ __launch_bounds__(256) void gemm_bf16(
    const __bf16* __restrict__ A, const __bf16* __restrict__ Bt,
    void* __restrict__ C, int M, int N, int K,
    const float* __restrict__ pbu, const float* __restrict__ pbv,
    __bf16* __restrict__ qup, __bf16* __restrict__ qvp)
{
  __shared__ __bf16 a_lds[128][40];
  __shared__ __bf16 b_lds[128][40];
  const int m0 = blockIdx.x * 128;
  const int n0 = blockIdx.y * 128;
  const int tid = threadIdx.x;
  const int w = tid >> 6, l = tid & 63;
  const int wn = (w >> 1) * 64, wm = (w & 1) * 64;
  const int li = l & 15, lq = l >> 4;
  const int lk = lq << 3;

  f32x4 acc[4][4] = {};

  for (int k0 = 0; k0 < K; k0 += 32) {
    __syncthreads();
#pragma unroll
    for (int c = 0; c < 2; ++c) {
      const int chunk = c * 256 + tid;
      const int row = chunk >> 2, kc = (chunk & 3) << 3;
      *(bhalf8*)&a_lds[row][kc] = *(const bhalf8*)(A + (size_t)(m0 + row) * K + k0 + kc);
      *(bhalf8*)&b_lds[row][kc] = *(const bhalf8*)(Bt + (size_t)(n0 + row) * K + k0 + kc);
    }
    __syncthreads();
    bhalf8 af[4], bf_[4];
#pragma unroll
    for (int s = 0; s < 4; ++s) {
      af[s]  = *(const bhalf8*)&b_lds[wn + s * 16 + li][lk];
      bf_[s] = *(const bhalf8*)&a_lds[wm + s * 16 + li][lk];
    }
#pragma unroll
    for (int ns = 0; ns < 4; ++ns)
#pragma unroll
      for (int ms = 0; ms < 4; ++ms)
        acc[ns][ms] = MFMA16(af[ns], bf_[ms], acc[ns][ms]);
  }

  const int lr = lq << 2;
#pragma unroll
  for (int ms = 0; ms < 4; ++ms) {
    const int m = m0 + wm + ms * 16 + li;
#pragma unroll
    for (int ns = 0; ns < 4; ++ns) {
      const int n = n0 + wn + ns * 16 + lr;
      if (OUT_MODE == 1) {
        *(f32x4*)((float*)C + (size_t)m * N + n) = acc[ns][ms];
      } else if (OUT_MODE == 0) {
        bhalf4 pk;
#pragma unroll
        for (int r = 0; r < 4; ++r) pk[r] = (__bf16)acc[ns][ms][r];
        *(bhalf4*)((__bf16*)C + (size_t)m * N + n) = pk;
      } else {
        const int i = m >> 2, bb = m & 3, hd = n >> 6;
        float4 u4 = *(const float4*)(pbu + n);
        float4 v4 = *(const float4*)(pbv + n);
        const size_t off = (((size_t)bb * 8 + hd) * 512 + i) * 64 + (n & 63);
        bhalf4 pu, pv;
        pu[0] = (__bf16)((acc[ns][ms][0] + u4.x) * 0.125f);
        pu[1] = (__bf16)((acc[ns][ms][1] + u4.y) * 0.125f);
        pu[2] = (__bf16)((acc[ns][ms][2] + u4.z) * 0.125f);
        pu[3] = (__bf16)((acc[ns][ms][3] + u4.w) * 0.125f);
        pv[0] = (__bf16)((acc[ns][ms][0] + v4.x) * 0.125f);
        pv[1] = (__bf16)((acc[ns][ms][1] + v4.y) * 0.125f);
        pv[2] = (__bf16)((acc[ns][ms][2] + v4.z) * 0.125f);
        pv[3] = (__bf16)((acc[ns][ms][3] + v4.w) * 0.125f);
        *(bhalf4*)(qup + off) = pu;
        *(bhalf4*)(qvp + off) = pv;
      }
    }
  }
}

// ---------------------------------------------------------------------------
// V transpose: vtb[plane][d][t]
// ---------------------------------------------------------------------------
__global__ __launch_bounds__(256) void vtrans(const __bf16* __restrict__ kvb,
                                              __bf16* __restrict__ vtb)
{
  __shared__ __bf16 T2[64][72];
  const int t0 = blockIdx.x * 64;
  const int p = blockIdx.y;
  const int b = p >> 3, n = p & 7;
  const int tid = threadIdx.x;
#pragma unroll
  for (int c = 0; c < 2; ++c) {
    const int e = c * 256 + tid;
    const int tl = e >> 3, d8 = (e & 7) << 3;
    bhalf8 v8 = *(const bhalf8*)(kvb + ((size_t)(t0 + tl) * 4 + b) * 1024 + 512 + n * 64 + d8);
#pragma unroll
    for (int j = 0; j < 8; ++j) T2[d8 + j][tl] = v8[j];
  }
  __syncthreads();
#pragma unroll
  for (int c = 0; c < 2; ++c) {
    const int e = c * 256 + tid;
    const int d = e >> 3, t8 = (e & 7) << 3;
    bhalf8 v = *(const bhalf8*)&T2[d][t8];
    *(bhalf8*)(vtb + ((size_t)p * 64 + d) * 2048 + t0 + t8) = v;
  }
}

// ---------------------------------------------------------------------------
// Fused flash attention. Additionally streams each tile's unnormalized P
// (bf16, exp(s - m_tile)) to pb[plane][i][t] and the tile max to
// ms[plane][tile][i], so attn_matrix needs no recompute.
// ---------------------------------------------------------------------------
__global__ __launch_bounds__(512, 4) void attn_v3(
    const __bf16* __restrict__ qup, const __bf16* __restrict__ qvp,
    const __bf16* __restrict__ kvb, const __bf16* __restrict__ relb,
    const __bf16* __restrict__ vtb, const float* __restrict__ indice,
    __bf16* __restrict__ vecb, float* __restrict__ ml,
    __bf16* __restrict__ pb, float* __restrict__ ms)
{
  __shared__ __align__(16) __bf16 P_l[32][136];
  __shared__ __align__(16) __bf16 bdl[160][33];
  __shared__ float red0[8][33];
  __shared__ float red1[8][33];
  __shared__ float lfin[32];

  const int bid = blockIdx.x;
  const int wrk = ((bid & 7) << 6) + (bid >> 3);
  const int plane = wrk >> 4;
  const int i0 = (wrk & 15) << 5;
  const int b = plane >> 3, n = plane & 7;
  const int tid = threadIdx.x;
  const int w = tid >> 6;
  const int l = tid & 63;
  const int li = l & 15;
  const int lq = l >> 4;

  const __bf16* kbase = kvb + (size_t)b * 1024 + n * 64;
  const __bf16* rbase = relb + (size_t)b * 512 + n * 64;
  const __bf16* vbase = vtb + (size_t)plane * 131072;

  bhalf8 qu[2][2], qv[2][2];
  float g[2][4];
#pragma unroll
  for (int it = 0; it < 2; ++it) {
    const int i = i0 + it * 16 + li;
    const float* gp = indice + ((size_t)i * 4 + b) * 4;
    g[it][0] = gp[0]; g[it][1] = gp[1]; g[it][2] = gp[2]; g[it][3] = gp[3];
    const __bf16* qp = qup + ((size_t)plane * 512 + i) * 64;
    const __bf16* qq = qvp + ((size_t)plane * 512 + i) * 64;
    qu[it][0] = *(const bhalf8*)(qp + lq * 8);
    qu[it][1] = *(const bhalf8*)(qp + 32 + lq * 8);
    qv[it][0] = *(const bhalf8*)(qq + lq * 8);
    qv[it][1] = *(const bhalf8*)(qq + 32 + lq * 8);
  }

  float m0 = -1e30f, m1 = -1e30f, l0 = 0.f, l1 = 0.f;
  f32x4 oacc = {0.f, 0.f, 0.f, 0.f};
  const int dgw = w >> 1, itw = w & 1;
  const int nt = ((1536 + i0 + 31) >> 7) + 1;

  for (int tile = 0; tile < nt; ++tile) {
    const int tb = tile << 7;
    const int rb = tb + 480 - i0;

    // ---- BD ----
#pragma unroll
    for (int ri = 0; ri < 2; ++ri) {
      const int rs = w + ri * 8;
      if (ri == 0 || rs < 10) {
        int row = rb + rs * 16 + li;
        row = row > 2047 ? 2047 : row;
        const __bf16* rp = rbase + (size_t)row * 2048;
        bhalf8 a0 = *(const bhalf8*)(rp + lq * 8);
        bhalf8 a1 = *(const bhalf8*)(rp + 32 + lq * 8);
#pragma unroll
        for (int it = 0; it < 2; ++it) {
          f32x4 c = {0.f, 0.f, 0.f, 0.f};
          c = MFMA16(a0, qv[it][0], c);
          c = MFMA16(a1, qv[it][1], c);
#pragma unroll
          for (int r = 0; r < 4; ++r) {
            const int rowl = rs * 16 + lq * 4 + r;
            int rk = (rb + rowl) >> 9; rk = rk > 3 ? 3 : rk;
            bdl[rowl][it * 16 + li] = (__bf16)(c[r] * g[it][rk]);
          }
        }
      }
    }
    // ---- AC ----
    f32x4 s[2];
    {
      const __bf16* kp = kbase + (size_t)(tb + w * 16 + li) * 4096;
      bhalf8 a0 = *(const bhalf8*)(kp + lq * 8);
      bhalf8 a1 = *(const bhalf8*)(kp + 32 + lq * 8);
#pragma unroll
      for (int it = 0; it < 2; ++it) {
        f32x4 c = {0.f, 0.f, 0.f, 0.f};
        c = MFMA16(a0, qu[it][0], c);
        c = MFMA16(a1, qu[it][1], c);
        s[it] = c;
      }
    }
    __syncthreads();   // bd visible

    float sv[2][4];
    float tmax[2] = {-1e30f, -1e30f};
#pragma unroll
    for (int it = 0; it < 2; ++it) {
      const int i = i0 + it * 16 + li;
#pragma unroll
      for (int r = 0; r < 4; ++r) {
        const int tl = w * 16 + lq * 4 + r;
        const int t = tb + tl;
        float sc = -1e30f;
        if (t <= 1536 + i) {
          const float bdv = (float)bdl[tl + 31 - it * 16 - li][it * 16 + li];
          sc = s[it][r] * g[it][t >> 9] + bdv;
        }
        sv[it][r] = sc;
        tmax[it] = fmaxf(tmax[it], sc);
      }
    }
    tmax[0] = fmaxf(tmax[0], __shfl_xor(tmax[0], 16));
    tmax[0] = fmaxf(tmax[0], __shfl_xor(tmax[0], 32));
    tmax[1] = fmaxf(tmax[1], __shfl_xor(tmax[1], 16));
    tmax[1] = fmaxf(tmax[1], __shfl_xor(tmax[1], 32));
    if (l < 16) { red0[w][li] = tmax[0]; red0[w][16 + li] = tmax[1]; }
    __syncthreads();

    float mn[2], scl[2];
#pragma unroll
    for (int it = 0; it < 2; ++it) {
      const int ic = it * 16 + li;
      float mt = red0[0][ic];
#pragma unroll
      for (int ww = 1; ww < 8; ++ww) mt = fmaxf(mt, red0[ww][ic]);
      const float mo = it ? m1 : m0;
      mn[it] = fmaxf(mo, mt);
      scl[it] = __expf(mo - mn[it]);
    }
    // record this tile's reference max for am_final
    if (w == 0 && l < 16) {
      float* msp = ms + ((size_t)plane * 16 + tile) * 512 + i0;
      msp[li] = mn[0];
      msp[16 + li] = mn[1];
    }
    float ps[2] = {0.f, 0.f};
#pragma unroll
    for (int it = 0; it < 2; ++it) {
      bhalf4 pk;
#pragma unroll
      for (int r = 0; r < 4; ++r) {
        const float p = __expf(sv[it][r] - mn[it]);
        ps[it] += p;
        pk[r] = (__bf16)p;
      }
      *(bhalf4*)&P_l[it * 16 + li][w * 16 + lq * 4] = pk;
    }
    ps[0] += __shfl_xor(ps[0], 16); ps[0] += __shfl_xor(ps[0], 32);
    ps[1] += __shfl_xor(ps[1], 16); ps[1] += __shfl_xor(ps[1], 32);
    if (l < 16) { red1[w][li] = ps[0]; red1[w][16 + li] = ps[1]; }
    __syncthreads();   // red1 + P_l visible

    // stream P tile to global (coalesced 16B/thread); safe until next tile's
    // first __syncthreads, which is after the next P_l writes' barrier.
    {
      const int iloc = tid >> 4, tq = tid & 15;
      bhalf8 pv8 = *(const bhalf8*)&P_l[iloc][tq * 8];
      *(bhalf8*)(pb + ((size_t)plane * 512 + i0 + iloc) * 2048 + tb + tq * 8) = pv8;
    }

    {
      float ls0 = 0.f, ls1 = 0.f;
#pragma unroll
      for (int ww = 0; ww < 8; ++ww) { ls0 += red1[ww][li]; ls1 += red1[ww][16 + li]; }
      l0 = l0 * scl[0] + ls0; m0 = mn[0];
      l1 = l1 * scl[1] + ls1; m1 = mn[1];
    }
    // ---- PV ----
    oacc *= scl[itw];
    {
      const __bf16* vp = vbase + (size_t)(dgw * 16 + li) * 2048 + tb;
#pragma unroll
      for (int kt = 0; kt < 4; ++kt) {
        bhalf8 af = *(const bhalf8*)(vp + kt * 32 + lq * 8);
        bhalf8 bf_ = *(const bhalf8*)&P_l[itw * 16 + li][kt * 32 + lq * 8];
        oacc = MFMA16(af, bf_, oacc);
      }
    }
  }

  __syncthreads();
  float* obuf = (float*)&P_l[0][0];
  if (w == 0 && l < 16) {
    lfin[li] = 1.f / l0;
    lfin[16 + li] = 1.f / l1;
    float* mp0 = ml + ((size_t)plane * 512 + i0 + li) * 2;
    mp0[0] = m0; mp0[1] = l0;
    float* mp1 = ml + ((size_t)plane * 512 + i0 + 16 + li) * 2;
    mp1[0] = m1; mp1[1] = l1;
  }
#pragma unroll
  for (int r = 0; r < 4; ++r)
    obuf[(itw * 16 + li) * 68 + dgw * 16 + lq * 4 + r] = oacc[r];
  __syncthreads();
  {
    const int iloc = tid >> 4, dq = tid & 15;
    const float rli = lfin[iloc];
    f32x4 o = *(f32x4*)&obuf[iloc * 68 + dq * 4];
    bhalf4 ov;
#pragma unroll
    for (int r = 0; r < 4; ++r) ov[r] = (__bf16)(o[r] * rli);
    *(bhalf4*)(vecb + ((size_t)(i0 + iloc) * 4 + b) * 512 + n * 64 + dq * 4) = ov;
  }
}

// ---------------------------------------------------------------------------
// am_final: am[i,t] = (1/32) sum_p pb[p][i][t] * exp(ms[p][tile][i]-m_fin)/l_fin
// One block per i-row (512 blocks, 256 thr, 8 t's/thread). Pure streaming.
// Unwritten (fully masked) tiles excluded via weight=0.
// ---------------------------------------------------------------------------
__global__ __launch_bounds__(256) void am_final(
    const __bf16* __restrict__ pb, const float* __restrict__ ms,
    const float* __restrict__ ml, float* __restrict__ am)
{
  const int i = blockIdx.x;
  const int tid = threadIdx.x;
  const int t0 = tid << 3;
  const int tile = t0 >> 7;
  const bool valid = tile <= ((1536 + (i | 31)) >> 7);
  f32x4 a0 = {0.f, 0.f, 0.f, 0.f}, a1 = {0.f, 0.f, 0.f, 0.f};
#pragma unroll 4
  for (int p = 0; p < 32; ++p) {
    const float2 mlv = *(const float2*)(ml + ((size_t)p * 512 + i) * 2);
    float wgt = 0.f;
    if (valid)
      wgt = __expf(ms[((size_t)p * 16 + tile) * 512 + i] - mlv.x) / mlv.y;
    bhalf8 v = *(const bhalf8*)(pb + ((size_t)p * 512 + i) * 2048 + t0);
    a0[0] += wgt * (float)v[0];
    a0[1] += wgt * (float)v[1];
    a0[2] += wgt * (float)v[2];
    a0[3] += wgt * (float)v[3];
    a1[0] += wgt * (float)v[4];
    a1[1] += wgt * (float)v[5];
    a1[2] += wgt * (float)v[6];
    a1[3] += wgt * (float)v[7];
  }
  const float sc = 1.f / 32.f;
  *(f32x4*)(am + (size_t)i * 2048 + t0)     = a0 * sc;
  *(f32x4*)(am + (size_t)i * 2048 + t0 + 4) = a1 * sc;
}

// ---------------------------------------------------------------------------
// Residual + LayerNorm
// ---------------------------------------------------------------------------
__global__ __launch_bounds__(256) void ln_f32(
    const float* __restrict__ x, const float* __restrict__ ao,
    const float* __restrict__ g, const float* __restrict__ bb,
    float* __restrict__ out)
{
  const int row = blockIdx.x;
  const int tid = threadIdx.x;
  const size_t base = (size_t)row * 512;
  const float y0 = x[base + tid] + ao[base + tid];
  const float y1 = x[base + 256 + tid] + ao[base + 256 + tid];
  float s  = y0 + y1;
  float ss = y0 * y0 + y1 * y1;
#pragma unroll
  for (int off = 32; off > 0; off >>= 1) {
    s  += __shfl_xor(s, off);
    ss += __shfl_xor(ss, off);
  }
  __shared__ float sred[4], ssred[4], stat[2];
  const int w = tid >> 6;
  if ((tid & 63) == 0) { sred[w] = s; ssred[w] = ss; }
  __syncthreads();
  if (tid == 0) {
    const float S  = sred[0] + sred[1] + sred[2] + sred[3];
    const float SS = ssred[0] + ssred[1] + ssred[2] + ssred[3];
    const float mu = S * (1.f / 512.f);
    const float var = SS * (1.f / 512.f) - mu * mu;
    stat[0] = mu;
    stat[1] = rsqrtf(var + 1e-5f);
  }
  __syncthreads();
  const float mu = stat[0], rs = stat[1];
  out[base + tid]       = (y0 - mu) * rs * g[tid] + bb[tid];
  out[base + 256 + tid] = (y1 - mu) * rs * g[256 + tid] + bb[256 + tid];
}

// ---------------------------------------------------------------------------
// Launch. ws layout (bf16 elem offsets):
//   cb    @ 0           4,194,304  (concat -> vtb after kv GEMM)
//   posb  @ 4,194,304   4,194,304  (pos -> aof f32 after rel GEMM)
//   kvb   @ 8,388,608   8,388,608
//   relb  @ 16,777,216  4,194,304
//   qup   @ 20,971,520  1,048,576
//   qvp   @ 22,020,096  1,048,576
//   vecb  @ 23,068,672  1,048,576
//   wqt   @ 24,117,248  262,144 / wkvt 524,288 / wrelt 262,144 / wot 262,144
//   ml    @ 25,427,968  (32,768 f32  = 65,536 elems)
//   ms    @ 25,493,504  (262,144 f32 = 524,288 elems)
//   pb    @ 26,017,792  33,554,432  (bf16, 67 MB)
//   total = 59,572,224 elems = ~119.2 MB
// ---------------------------------------------------------------------------
extern "C" void kernel_launch(void* const* d_in, const int* in_sizes, int n_in,
                              void* d_out, int out_size, void* d_ws, size_t ws_size,
                              hipStream_t stream)
{
  (void)in_sizes; (void)n_in; (void)out_size; (void)ws_size;
  const float* x      = (const float*)d_in[0];
  const float* memory = (const float*)d_in[1];
  const float* pos    = (const float*)d_in[2];
  const float* pbu    = (const float*)d_in[3];
  const float* pbv    = (const float*)d_in[4];
  const float* indice = (const float*)d_in[6];
  const float* W_q    = (const float*)d_in[7];
  const float* W_kv   = (const float*)d_in[8];
  const float* W_rel  = (const float*)d_in[9];
  const float* W_o    = (const float*)d_in[10];
  const float* ln_g   = (const float*)d_in[11];
  const float* ln_b   = (const float*)d_in[12];

  float* out = (float*)d_out;
  float* am  = out + 1048576;

  __bf16* cb    = (__bf16*)d_ws;
  __bf16* posb  = cb + 4194304;
  __bf16* kvb   = posb + 4194304;
  __bf16* relb  = kvb + 8388608;
  __bf16* qup   = relb + 4194304;
  __bf16* qvp   = qup + 1048576;
  __bf16* vecb  = qvp + 1048576;
  __bf16* wqt   = vecb + 1048576;
  __bf16* wkvt  = wqt + 262144;
  __bf16* wrelt = wkvt + 524288;
  __bf16* wot   = wrelt + 262144;
  float*  ml    = (float*)(wot + 262144);
  float*  ms    = ml + 32768;
  __bf16* pbuf  = (__bf16*)(ms + 262144);
  __bf16* xb    = cb + 3145728;          // x rows start at concat row 6144
  __bf16* vtb   = cb;                    // reuses cb after kv GEMM
  float*  aof   = (float*)posb;          // reuses posb after rel GEMM

  cast_bf16<<<3072, 256, 0, stream>>>(memory, cb, 786432);
  cast_bf16<<<1024, 256, 0, stream>>>(x, xb, 262144);
  cast_bf16<<<4096, 256, 0, stream>>>(pos, posb, 1048576);
  transcast<<<dim3(8, 128), 256, 0, stream>>>(W_q,   wqt,   512, 512);
  transcast<<<dim3(8, 256), 256, 0, stream>>>(W_kv,  wkvt,  512, 1024);
  transcast<<<dim3(8, 128), 256, 0, stream>>>(W_rel, wrelt, 512, 512);
  transcast<<<dim3(8, 128), 256, 0, stream>>>(W_o,   wot,   512, 512);

  gemm_bf16<2><<<dim3(16, 4), 256, 0, stream>>>(xb, wqt, (void*)qup, 2048, 512, 512,
                                                pbu, pbv, qup, qvp);
  gemm_bf16<0><<<dim3(64, 8), 256, 0, stream>>>(cb, wkvt, kvb, 8192, 1024, 512,
                                                nullptr, nullptr, nullptr, nullptr);
  gemm_bf16<0><<<dim3(64, 4), 256, 0, stream>>>(posb, wrelt, relb, 8192, 512, 512,
                                                nullptr, nullptr, nullptr, nullptr);

  vtrans<<<dim3(32, 32), 256, 0, stream>>>(kvb, vtb);

  attn_v3<<<512, 512, 0, stream>>>(qup, qvp, kvb, relb, vtb, indice, vecb, ml,
                                   pbuf, ms);

  am_final<<<512, 256, 0, stream>>>(pbuf, ms, ml, am);

  gemm_bf16<1><<<dim3(16, 4), 256, 0, stream>>>(vecb, wot, aof, 2048, 512, 512,
                                                nullptr, nullptr, nullptr, nullptr);
  ln_f32<<<2048, 256, 0, stream>>>(x, aof, ln_g, ln_b, out);
}